// Round 10
// baseline (321.282 us; speedup 1.0000x reference)
//
#include <hip/hip_runtime.h>

#define DIM 64
#define CHUNK 8192      // edges per partition block
#define MAXNB 1024      // max coarse buckets (N <= 524288 with BSHIFT=9)
#define BSHIFT 9
#define RPB 512         // rows per bucket (1 << BSHIFT)
#define PADMASK 7       // rows padded to multiple of 8
#define CONVB 512       // conv blocks appended to p1c grid (sepEmb mode)

__device__ __forceinline__ unsigned short f2bf(float f) {
    unsigned int u = __float_as_uint(f);
    return (unsigned short)((u + 0x7FFFu + ((u >> 16) & 1u)) >> 16);  // RNE
}
__device__ __forceinline__ float4 bf2f4(unsigned int lo, unsigned int hi) {
    float4 x;
    x.x = __uint_as_float(lo << 16);
    x.y = __uint_as_float(lo & 0xffff0000u);
    x.z = __uint_as_float(hi << 16);
    x.w = __uint_as_float(hi & 0xffff0000u);
    return x;
}
__device__ __forceinline__ float4 bf2f4(uint2 g) { return bf2f4(g.x, g.y); }

// inclusive block scan over 256 per-thread values; sh[255] = total after call
__device__ __forceinline__ int blockScan256(int v, int* sh) {
    int t = threadIdx.x;
    sh[t] = v;
    __syncthreads();
    for (int off = 1; off < 256; off <<= 1) {
        int x = (t >= off) ? sh[t - off] : 0;
        __syncthreads();
        sh[t] += x;
        __syncthreads();
    }
    return sh[t];
}

// ---------------- f32 -> packed bf16 conversion (fallback standalone) ----------------

__global__ void conv2_k(const float* __restrict__ u, const float* __restrict__ it,
                        int nu, int ntot, unsigned short* __restrict__ o) {
    int i = blockIdx.x * blockDim.x + threadIdx.x;
    int stride = gridDim.x * blockDim.x;
    int n8 = ntot >> 3;
    for (int t = i; t < n8; t += stride) {
        int e = t * 8;
        const float* src = (e < nu) ? (u + e) : (it + (e - nu));
        float4 x = *(const float4*)src;
        float4 y = *(const float4*)(src + 4);
        uint4 v;
        v.x = (unsigned)f2bf(x.x) | ((unsigned)f2bf(x.y) << 16);
        v.y = (unsigned)f2bf(x.z) | ((unsigned)f2bf(x.w) << 16);
        v.z = (unsigned)f2bf(y.x) | ((unsigned)f2bf(y.y) << 16);
        v.w = (unsigned)f2bf(y.z) | ((unsigned)f2bf(y.w) << 16);
        ((uint4*)o)[t] = v;
    }
}

// ---------------- two-level counting sort (no global atomics) ----------------

__global__ void p1a_hist(const int* __restrict__ row, int E, int NB,
                         int* __restrict__ counts) {
    __shared__ int h[MAXNB];
    for (int b = threadIdx.x; b < NB; b += 256) h[b] = 0;
    __syncthreads();
    int base = blockIdx.x * CHUNK;
    int end = min(base + CHUNK, E);
    int vend = base + ((end - base) & ~3);
    for (int i = base + threadIdx.x * 4; i < vend; i += 1024) {
        int4 r = *(const int4*)(row + i);
        atomicAdd(&h[r.x >> BSHIFT], 1);
        atomicAdd(&h[r.y >> BSHIFT], 1);
        atomicAdd(&h[r.z >> BSHIFT], 1);
        atomicAdd(&h[r.w >> BSHIFT], 1);
    }
    for (int i = vend + threadIdx.x; i < end; i += 256) atomicAdd(&h[row[i] >> BSHIFT], 1);
    __syncthreads();
    int blk = blockIdx.x;
    for (int b = threadIdx.x; b < NB; b += 256) counts[(size_t)blk * NB + b] = h[b];
}

__global__ void p1b_scan(int* __restrict__ counts, int NBLK, int NB,
                         int* __restrict__ bucketTotal) {
    int b = blockIdx.x, t = threadIdx.x;
    __shared__ int sh[256];
    int v[8];
    int run = 0;
#pragma unroll
    for (int i = 0; i < 8; i++) {
        int idx = t * 8 + i;
        int c = (idx < NBLK) ? counts[(size_t)idx * NB + b] : 0;
        v[i] = run;  // exclusive within thread
        run += c;
    }
    int inc = blockScan256(run, sh);
    int excl = inc - run;
#pragma unroll
    for (int i = 0; i < 8; i++) {
        int idx = t * 8 + i;
        if (idx < NBLK) counts[(size_t)idx * NB + b] = v[i] + excl;
    }
    if (t == 255) bucketTotal[b] = sh[255];
}

__global__ void p_scan_tot(const int* __restrict__ bucketTotal, int NB,
                           int* __restrict__ bucketStart) {
    int t = threadIdx.x;
    __shared__ int sh[256];
    int v[8];
    int run = 0;
#pragma unroll
    for (int i = 0; i < 8; i++) {
        int idx = t * 8 + i;
        int c = (idx < NB) ? bucketTotal[idx] : 0;
        v[i] = run;
        run += c;
    }
    int inc = blockScan256(run, sh);
    int excl = inc - run;
#pragma unroll
    for (int i = 0; i < 8; i++) {
        int idx = t * 8 + i;
        if (idx < NB) bucketStart[idx] = v[i] + excl;
    }
    if (t == 255) bucketStart[NB] = sh[255];
}

// P1c (bucket scatter) + heterogeneous conv blocks (blk >= NBLK do the bf16 pack).
__global__ void p1c_conv(const int* __restrict__ row, const int* __restrict__ col,
                         const float* __restrict__ vals, int E, int NB,
                         const int* __restrict__ counts, const int* __restrict__ bucketStart,
                         int2* __restrict__ bdata, int NBLK,
                         const float* __restrict__ u, const float* __restrict__ it,
                         int nu, int ntot, unsigned short* __restrict__ o) {
    __shared__ int cur[MAXNB];
    int blk = blockIdx.x;
    if (blk < NBLK) {
        for (int b = threadIdx.x; b < NB; b += 256)
            cur[b] = bucketStart[b] + counts[(size_t)blk * NB + b];
        __syncthreads();
        int base = blk * CHUNK;
        int end = min(base + CHUNK, E);
        int vend = base + ((end - base) & ~3);
        for (int i = base + threadIdx.x * 4; i < vend; i += 1024) {
            int4 r = *(const int4*)(row + i);
            int4 c = *(const int4*)(col + i);
            float4 v = *(const float4*)(vals + i);
            int p0 = atomicAdd(&cur[r.x >> BSHIFT], 1);
            int p1 = atomicAdd(&cur[r.y >> BSHIFT], 1);
            int p2 = atomicAdd(&cur[r.z >> BSHIFT], 1);
            int p3 = atomicAdd(&cur[r.w >> BSHIFT], 1);
            bdata[p0] = make_int2(((r.x & (RPB - 1)) << 20) | c.x, __float_as_int(v.x));
            bdata[p1] = make_int2(((r.y & (RPB - 1)) << 20) | c.y, __float_as_int(v.y));
            bdata[p2] = make_int2(((r.z & (RPB - 1)) << 20) | c.z, __float_as_int(v.z));
            bdata[p3] = make_int2(((r.w & (RPB - 1)) << 20) | c.w, __float_as_int(v.w));
        }
        for (int i = vend + threadIdx.x; i < end; i += 256) {
            int r = row[i];
            int p = atomicAdd(&cur[r >> BSHIFT], 1);
            bdata[p] = make_int2(((r & (RPB - 1)) << 20) | col[i], __float_as_int(vals[i]));
        }
    } else {
        int cb = blk - NBLK;
        int nConv = gridDim.x - NBLK;
        int i = cb * 256 + threadIdx.x;
        int stride = nConv * 256;
        int n8 = ntot >> 3;
        for (int t = i; t < n8; t += stride) {
            int e = t * 8;
            const float* src = (e < nu) ? (u + e) : (it + (e - nu));
            float4 x = *(const float4*)src;
            float4 y = *(const float4*)(src + 4);
            uint4 v;
            v.x = (unsigned)f2bf(x.x) | ((unsigned)f2bf(x.y) << 16);
            v.y = (unsigned)f2bf(x.z) | ((unsigned)f2bf(x.w) << 16);
            v.z = (unsigned)f2bf(y.x) | ((unsigned)f2bf(y.y) << 16);
            v.w = (unsigned)f2bf(y.z) | ((unsigned)f2bf(y.w) << 16);
            ((uint4*)o)[t] = v;
        }
    }
}

// P2: per-bucket regroup by exact row into PADDED rows (pads = colOff 0, val 0).
// pairs.x stores col*128 (byte offset). Only pad slots are filled post-scatter.
__global__ void p2_group(const int2* __restrict__ bdata, const int* __restrict__ bucketStart,
                         int NB, int N, int padSlop,
                         int* __restrict__ rowStart, int* __restrict__ rowLen,
                         int2* __restrict__ pairs) {
    __shared__ int hist[RPB];
    __shared__ int sh[256];
    __shared__ int cur[RPB];
    int b = blockIdx.x, t = threadIdx.x;
    int s0 = bucketStart[b], s1 = bucketStart[b + 1];
    int pbase = s0 + b * padSlop;
    for (int i = t; i < RPB; i += 256) hist[i] = 0;
    __syncthreads();
    for (int i = s0 + t; i < s1; i += 256)
        atomicAdd(&hist[(bdata[i].x >> 20) & (RPB - 1)], 1);
    __syncthreads();
    int v[2];
    int run = 0;
#pragma unroll
    for (int i = 0; i < 2; i++) {
        int h = hist[t * 2 + i];
        int hp = (h + PADMASK) & ~PADMASK;
        v[i] = run;  // exclusive within thread
        run += hp;
    }
    int inc = blockScan256(run, sh);
    int excl = inc - run;
#pragma unroll
    for (int i = 0; i < 2; i++) {
        int r = (b << BSHIFT) + t * 2 + i;
        int st = excl + v[i];
        if (r < N) {
            int h = hist[t * 2 + i];
            rowStart[r] = pbase + st;
            rowLen[r] = (h + PADMASK) & ~PADMASK;
        }
        cur[t * 2 + i] = st;
    }
    __syncthreads();
    // scatter real edges into row-grouped slots
    for (int i = s0 + t; i < s1; i += 256) {
        int2 e = bdata[i];
        int rl = (e.x >> 20) & (RPB - 1);
        int pos = atomicAdd(&cur[rl], 1);
        pairs[pbase + pos] = make_int2((e.x & 0xFFFFF) << 7, e.y);
    }
    __syncthreads();
    // fill ONLY the pad slots (colOff=0 -> row 0, val=0)
#pragma unroll
    for (int i = 0; i < 2; i++) {
        int h = hist[t * 2 + i];
        int hp = (h + PADMASK) & ~PADMASK;
        int st = excl + v[i];
        for (int p = st + h; p < st + hp; p++)
            pairs[pbase + p] = make_int2(0, 0);
    }
}

// ---------------- layer-1 SpMM: wave per row, 8 edge-groups x 8 dim-octs ----------------

__global__ void spmm1_k(const unsigned short* __restrict__ emb16,
                        const int* __restrict__ rowStart, const int* __restrict__ rowLen,
                        const int2* __restrict__ pairs,
                        int n_total, unsigned short* __restrict__ e1) {
    int wave = (blockIdx.x * blockDim.x + threadIdx.x) >> 6;
    int lane = threadIdx.x & 63;
    if (wave >= n_total) return;
    int eg = lane >> 3, dp = lane & 7;   // 8 edge groups, 8 dim-octs
    unsigned off0 = dp * 16u;            // byte offset of this lane's 8 bf16 dims
    const char* base = (const char*)emb16;
    int len = rowLen[wave];
    const int2* pp = pairs + rowStart[wave];
    float4 aA0 = {0.f, 0.f, 0.f, 0.f}, aA1 = {0.f, 0.f, 0.f, 0.f};
    float4 aB0 = {0.f, 0.f, 0.f, 0.f}, aB1 = {0.f, 0.f, 0.f, 0.f};
    int k = 0;
    for (; k + 16 <= len; k += 16) {
        int4 q = *(const int4*)(pp + k + 2 * eg);   // edges k+2eg, k+2eg+1
        uint4 g0 = *(const uint4*)(base + ((unsigned)q.x + off0));
        uint4 g1 = *(const uint4*)(base + ((unsigned)q.z + off0));
        float v0 = __int_as_float(q.y), v1 = __int_as_float(q.w);
        float4 x0 = bf2f4(g0.x, g0.y), x1 = bf2f4(g0.z, g0.w);
        float4 y0 = bf2f4(g1.x, g1.y), y1 = bf2f4(g1.z, g1.w);
        aA0.x += v0 * x0.x; aA0.y += v0 * x0.y; aA0.z += v0 * x0.z; aA0.w += v0 * x0.w;
        aA1.x += v0 * x1.x; aA1.y += v0 * x1.y; aA1.z += v0 * x1.z; aA1.w += v0 * x1.w;
        aB0.x += v1 * y0.x; aB0.y += v1 * y0.y; aB0.z += v1 * y0.z; aB0.w += v1 * y0.w;
        aB1.x += v1 * y1.x; aB1.y += v1 * y1.y; aB1.z += v1 * y1.z; aB1.w += v1 * y1.w;
    }
    if (k < len) {  // one trailing 8-block: edge k+eg (one per group)
        int2 p = pp[k + eg];
        uint4 g0 = *(const uint4*)(base + ((unsigned)p.x + off0));
        float v0 = __int_as_float(p.y);
        float4 x0 = bf2f4(g0.x, g0.y), x1 = bf2f4(g0.z, g0.w);
        aA0.x += v0 * x0.x; aA0.y += v0 * x0.y; aA0.z += v0 * x0.z; aA0.w += v0 * x0.w;
        aA1.x += v0 * x1.x; aA1.y += v0 * x1.y; aA1.z += v0 * x1.z; aA1.w += v0 * x1.w;
    }
    float4 s0, s1;
    s0.x = aA0.x + aB0.x; s0.y = aA0.y + aB0.y; s0.z = aA0.z + aB0.z; s0.w = aA0.w + aB0.w;
    s1.x = aA1.x + aB1.x; s1.y = aA1.y + aB1.y; s1.z = aA1.z + aB1.z; s1.w = aA1.w + aB1.w;
#pragma unroll
    for (int m = 8; m <= 32; m <<= 1) {
        s0.x += __shfl_xor(s0.x, m); s0.y += __shfl_xor(s0.y, m);
        s0.z += __shfl_xor(s0.z, m); s0.w += __shfl_xor(s0.w, m);
        s1.x += __shfl_xor(s1.x, m); s1.y += __shfl_xor(s1.y, m);
        s1.z += __shfl_xor(s1.z, m); s1.w += __shfl_xor(s1.w, m);
    }
    if (eg == 0) {
        uint4 o;
        o.x = (unsigned)f2bf(s0.x) | ((unsigned)f2bf(s0.y) << 16);
        o.y = (unsigned)f2bf(s0.z) | ((unsigned)f2bf(s0.w) << 16);
        o.z = (unsigned)f2bf(s1.x) | ((unsigned)f2bf(s1.y) << 16);
        o.w = (unsigned)f2bf(s1.z) | ((unsigned)f2bf(s1.w) << 16);
        *(uint4*)(e1 + (size_t)wave * DIM + dp * 8) = o;
    }
}

// ---------------- fused layer-2 + gather + dot epilogue ----------------

__global__ void final_k(const float* __restrict__ emb_user, const float* __restrict__ emb_item,
                        int n_user, const unsigned short* __restrict__ e1,
                        const int* __restrict__ rowStart, const int* __restrict__ rowLen,
                        const int2* __restrict__ pairs,
                        const int* __restrict__ u_nodes, const int* __restrict__ p_nodes,
                        const int* __restrict__ n_nodes, int B, float* __restrict__ out) {
    int wave = (blockIdx.x * blockDim.x + threadIdx.x) >> 6;
    int lane = threadIdx.x & 63;
    if (wave >= B) return;
    int eg = lane >> 4, dp = lane & 15;
    unsigned off0 = dp * 8u;
    const char* base = (const char*)e1;
    int nid[3] = {u_nodes[wave], p_nodes[wave], n_nodes[wave]};
    float4 l[3];
#pragma unroll
    for (int j = 0; j < 3; j++) {
        int r = nid[j];
        const float* base0 = (r < n_user) ? (emb_user + (size_t)r * DIM)
                                          : (emb_item + (size_t)(r - n_user) * DIM);
        float4 acc = *(const float4*)(base0 + dp * 4);                       // layer0 f32
        float4 t1 = bf2f4(*(const uint2*)(e1 + (size_t)r * DIM + dp * 4));   // layer1
        acc.x += t1.x; acc.y += t1.y; acc.z += t1.z; acc.w += t1.w;
        int len = rowLen[r];
        const int2* pp = pairs + rowStart[r];
        float4 a0 = {0.f, 0.f, 0.f, 0.f}, a1 = {0.f, 0.f, 0.f, 0.f};
        float4 a2 = {0.f, 0.f, 0.f, 0.f}, a3 = {0.f, 0.f, 0.f, 0.f};
        int k = 0;
        for (; k + 16 <= len; k += 16) {
            int4 q0 = *(const int4*)(pp + k + 2 * eg);
            int4 q1 = *(const int4*)(pp + k + 8 + 2 * eg);
            uint2 g0 = *(const uint2*)(base + ((unsigned)q0.x + off0));
            uint2 g1 = *(const uint2*)(base + ((unsigned)q0.z + off0));
            uint2 g2 = *(const uint2*)(base + ((unsigned)q1.x + off0));
            uint2 g3 = *(const uint2*)(base + ((unsigned)q1.z + off0));
            float v0 = __int_as_float(q0.y), v1 = __int_as_float(q0.w);
            float v2 = __int_as_float(q1.y), v3 = __int_as_float(q1.w);
            float4 x0 = bf2f4(g0), x1 = bf2f4(g1), x2 = bf2f4(g2), x3 = bf2f4(g3);
            a0.x += v0 * x0.x; a0.y += v0 * x0.y; a0.z += v0 * x0.z; a0.w += v0 * x0.w;
            a1.x += v1 * x1.x; a1.y += v1 * x1.y; a1.z += v1 * x1.z; a1.w += v1 * x1.w;
            a2.x += v2 * x2.x; a2.y += v2 * x2.y; a2.z += v2 * x2.z; a2.w += v2 * x2.w;
            a3.x += v3 * x3.x; a3.y += v3 * x3.y; a3.z += v3 * x3.z; a3.w += v3 * x3.w;
        }
        for (; k < len; k += 8) {
            int4 q0 = *(const int4*)(pp + k + 2 * eg);
            uint2 g0 = *(const uint2*)(base + ((unsigned)q0.x + off0));
            uint2 g1 = *(const uint2*)(base + ((unsigned)q0.z + off0));
            float v0 = __int_as_float(q0.y), v1 = __int_as_float(q0.w);
            float4 x0 = bf2f4(g0), x1 = bf2f4(g1);
            a0.x += v0 * x0.x; a0.y += v0 * x0.y; a0.z += v0 * x0.z; a0.w += v0 * x0.w;
            a1.x += v1 * x1.x; a1.y += v1 * x1.y; a1.z += v1 * x1.z; a1.w += v1 * x1.w;
        }
        float4 s;
        s.x = (a0.x + a1.x) + (a2.x + a3.x);
        s.y = (a0.y + a1.y) + (a2.y + a3.y);
        s.z = (a0.z + a1.z) + (a2.z + a3.z);
        s.w = (a0.w + a1.w) + (a2.w + a3.w);
        s.x += __shfl_xor(s.x, 16); s.y += __shfl_xor(s.y, 16);
        s.z += __shfl_xor(s.z, 16); s.w += __shfl_xor(s.w, 16);
        s.x += __shfl_xor(s.x, 32); s.y += __shfl_xor(s.y, 32);
        s.z += __shfl_xor(s.z, 32); s.w += __shfl_xor(s.w, 32);
        l[j].x = (acc.x + s.x) * (1.0f / 3.0f);
        l[j].y = (acc.y + s.y) * (1.0f / 3.0f);
        l[j].z = (acc.z + s.z) * (1.0f / 3.0f);
        l[j].w = (acc.w + s.w) * (1.0f / 3.0f);
    }
    float ps = l[0].x * l[1].x + l[0].y * l[1].y + l[0].z * l[1].z + l[0].w * l[1].w;
    float ns = l[0].x * l[2].x + l[0].y * l[2].y + l[0].z * l[2].z + l[0].w * l[2].w;
    ps += __shfl_xor(ps, 1); ns += __shfl_xor(ns, 1);
    ps += __shfl_xor(ps, 2); ns += __shfl_xor(ns, 2);
    ps += __shfl_xor(ps, 4); ns += __shfl_xor(ns, 4);
    ps += __shfl_xor(ps, 8); ns += __shfl_xor(ns, 8);
    if (lane == 0) {
        out[wave] = ps;
        out[B + wave] = ns;
    }
}

extern "C" void kernel_launch(void* const* d_in, const int* in_sizes, int n_in,
                              void* d_out, int out_size, void* d_ws, size_t ws_size,
                              hipStream_t stream) {
    const float* emb_user = (const float*)d_in[0];
    const float* emb_item = (const float*)d_in[1];
    const float* gvals    = (const float*)d_in[2];
    const int*   grow     = (const int*)d_in[3];
    const int*   gcol     = (const int*)d_in[4];
    const int*   unodes   = (const int*)d_in[5];
    const int*   pnodes   = (const int*)d_in[6];
    const int*   nnodes   = (const int*)d_in[7];
    float* out = (float*)d_out;

    int n_user = in_sizes[0] / DIM;
    int n_item = in_sizes[1] / DIM;
    int N = n_user + n_item;
    int E = in_sizes[2];
    int B = in_sizes[5];
    int NB = (N + RPB - 1) >> BSHIFT;
    int NBLK = (E + CHUNK - 1) / CHUNK;
    int padSlop = RPB * PADMASK;

    auto align256 = [](size_t x) { return (x + 255) & ~(size_t)255; };
    size_t embBytes = (size_t)N * DIM * 2;
    size_t countsBytes = (size_t)NBLK * NB * 4;
    size_t bdataBytes = (size_t)E * 8;
    size_t regionABytes = countsBytes > embBytes ? countsBytes : embBytes;  // counts / e1
    size_t pairsBytes = ((size_t)E + (size_t)NB * padSlop) * 8;
    size_t fixedBytes = align256((size_t)N * 4) * 2 + align256((size_t)MAXNB * 4) +
                        align256((size_t)(MAXNB + 1) * 4) + align256(pairsBytes) +
                        align256(regionABytes);
    // preferred: emb16 separate from bdata -> conv can run inside p1c (before bdata dies)
    bool sepEmb = fixedBytes + align256(bdataBytes) + align256(embBytes) <= ws_size;

    char* ws = (char*)d_ws;
    size_t off = 0;
    auto alloc = [&](size_t bytes) -> void* {
        void* p = ws + off;
        off = (off + bytes + 255) & ~(size_t)255;
        return p;
    };
    int*  rowStart    = (int*)alloc((size_t)N * 4);
    int*  rowLen      = (int*)alloc((size_t)N * 4);
    int*  bucketTotal = (int*)alloc((size_t)MAXNB * 4);
    int*  bucketStart = (int*)alloc((size_t)(MAXNB + 1) * 4);
    int2* pairs       = (int2*)alloc(pairsBytes);
    int2* bdata;
    unsigned short* emb16;
    if (sepEmb) {
        bdata = (int2*)alloc(bdataBytes);
        emb16 = (unsigned short*)alloc(embBytes);
    } else {
        char* regionB = (char*)alloc(bdataBytes > embBytes ? bdataBytes : embBytes);
        bdata = (int2*)regionB;            // dead after p2
        emb16 = (unsigned short*)regionB;  // written after p2 (overlay)
    }
    char* regionA = (char*)alloc(regionABytes);
    int*            counts = (int*)regionA;  // dead after p1c
    unsigned short* e1     = (unsigned short*)regionA;
    (void)n_in; (void)out_size;

    // CSR build via two-level counting sort (no global atomics)
    p1a_hist<<<NBLK, 256, 0, stream>>>(grow, E, NB, counts);
    p1b_scan<<<NB, 256, 0, stream>>>(counts, NBLK, NB, bucketTotal);
    p_scan_tot<<<1, 256, 0, stream>>>(bucketTotal, NB, bucketStart);
    int nConv = sepEmb ? CONVB : 0;
    p1c_conv<<<NBLK + nConv, 256, 0, stream>>>(grow, gcol, gvals, E, NB, counts, bucketStart,
                                               bdata, NBLK,
                                               emb_user, emb_item, n_user * DIM, N * DIM, emb16);
    p2_group<<<NB, 256, 0, stream>>>(bdata, bucketStart, NB, N, padSlop,
                                     rowStart, rowLen, pairs);
    if (!sepEmb)  // overlay layout: pack after bdata is dead
        conv2_k<<<2048, 256, 0, stream>>>(emb_user, emb_item, n_user * DIM, N * DIM, emb16);

    // layer-1 SpMM over all rows (e1 overlays dead counts)
    spmm1_k<<<(N + 3) / 4, 256, 0, stream>>>(emb16, rowStart, rowLen, pairs, N, e1);
    // fused layer-2 + gather + dots
    final_k<<<(B + 3) / 4, 256, 0, stream>>>(emb_user, emb_item, n_user, e1,
                                             rowStart, rowLen, pairs,
                                             unodes, pnodes, nnodes, B, out);
}

// Round 11
// 303.506 us; speedup vs baseline: 1.0586x; 1.0586x over previous
//
#include <hip/hip_runtime.h>

#define DIM 64
#define CHUNK 16384     // edges per partition block (run length = CHUNK/NB ~ 56 edges)
#define MAXNB 512       // max coarse buckets (N <= 524288 with BSHIFT=10)
#define BSHIFT 10
#define RPB 1024        // rows per bucket (1 << BSHIFT)
#define PADMASK 7       // rows padded to multiple of 8

__device__ __forceinline__ unsigned short f2bf(float f) {
    unsigned int u = __float_as_uint(f);
    return (unsigned short)((u + 0x7FFFu + ((u >> 16) & 1u)) >> 16);  // RNE
}
__device__ __forceinline__ float4 bf2f4(unsigned int lo, unsigned int hi) {
    float4 x;
    x.x = __uint_as_float(lo << 16);
    x.y = __uint_as_float(lo & 0xffff0000u);
    x.z = __uint_as_float(hi << 16);
    x.w = __uint_as_float(hi & 0xffff0000u);
    return x;
}
__device__ __forceinline__ float4 bf2f4(uint2 g) { return bf2f4(g.x, g.y); }

// inclusive block scan over 256 per-thread values; sh[255] = total after call
__device__ __forceinline__ int blockScan256(int v, int* sh) {
    int t = threadIdx.x;
    sh[t] = v;
    __syncthreads();
    for (int off = 1; off < 256; off <<= 1) {
        int x = (t >= off) ? sh[t - off] : 0;
        __syncthreads();
        sh[t] += x;
        __syncthreads();
    }
    return sh[t];
}

// ---------------- f32 -> packed bf16 conversion (both tables, one launch) ----------------

__global__ void conv2_k(const float* __restrict__ u, const float* __restrict__ it,
                        int nu, int ntot, unsigned short* __restrict__ o) {
    int i = blockIdx.x * blockDim.x + threadIdx.x;
    int stride = gridDim.x * blockDim.x;
    int n8 = ntot >> 3;
    for (int t = i; t < n8; t += stride) {
        int e = t * 8;
        const float* src = (e < nu) ? (u + e) : (it + (e - nu));
        float4 x = *(const float4*)src;
        float4 y = *(const float4*)(src + 4);
        uint4 v;
        v.x = (unsigned)f2bf(x.x) | ((unsigned)f2bf(x.y) << 16);
        v.y = (unsigned)f2bf(x.z) | ((unsigned)f2bf(x.w) << 16);
        v.z = (unsigned)f2bf(y.x) | ((unsigned)f2bf(y.y) << 16);
        v.w = (unsigned)f2bf(y.z) | ((unsigned)f2bf(y.w) << 16);
        ((uint4*)o)[t] = v;
    }
}

// ---------------- two-level counting sort (no global atomics) ----------------

__global__ void p1a_hist(const int* __restrict__ row, int E, int NB,
                         int* __restrict__ counts) {
    __shared__ int h[MAXNB];
    for (int b = threadIdx.x; b < NB; b += 256) h[b] = 0;
    __syncthreads();
    int base = blockIdx.x * CHUNK;
    int end = min(base + CHUNK, E);
    int vend = base + ((end - base) & ~3);
    for (int i = base + threadIdx.x * 4; i < vend; i += 1024) {
        int4 r = *(const int4*)(row + i);
        atomicAdd(&h[r.x >> BSHIFT], 1);
        atomicAdd(&h[r.y >> BSHIFT], 1);
        atomicAdd(&h[r.z >> BSHIFT], 1);
        atomicAdd(&h[r.w >> BSHIFT], 1);
    }
    for (int i = vend + threadIdx.x; i < end; i += 256) atomicAdd(&h[row[i] >> BSHIFT], 1);
    __syncthreads();
    int blk = blockIdx.x;
    for (int b = threadIdx.x; b < NB; b += 256) counts[(size_t)blk * NB + b] = h[b];
}

__global__ void p1b_scan(int* __restrict__ counts, int NBLK, int NB,
                         int* __restrict__ bucketTotal) {
    int b = blockIdx.x, t = threadIdx.x;
    __shared__ int sh[256];
    int v[8];
    int run = 0;
#pragma unroll
    for (int i = 0; i < 8; i++) {
        int idx = t * 8 + i;
        int c = (idx < NBLK) ? counts[(size_t)idx * NB + b] : 0;
        v[i] = run;  // exclusive within thread
        run += c;
    }
    int inc = blockScan256(run, sh);
    int excl = inc - run;
#pragma unroll
    for (int i = 0; i < 8; i++) {
        int idx = t * 8 + i;
        if (idx < NBLK) counts[(size_t)idx * NB + b] = v[i] + excl;
    }
    if (t == 255) bucketTotal[b] = sh[255];
}

__global__ void p_scan_tot(const int* __restrict__ bucketTotal, int NB,
                           int* __restrict__ bucketStart) {
    int t = threadIdx.x;
    __shared__ int sh[256];
    int v[8];
    int run = 0;
#pragma unroll
    for (int i = 0; i < 8; i++) {
        int idx = t * 8 + i;
        int c = (idx < NB) ? bucketTotal[idx] : 0;
        v[i] = run;
        run += c;
    }
    int inc = blockScan256(run, sh);
    int excl = inc - run;
#pragma unroll
    for (int i = 0; i < 8; i++) {
        int idx = t * 8 + i;
        if (idx < NB) bucketStart[idx] = v[i] + excl;
    }
    if (t == 255) bucketStart[NB] = sh[255];
}

__global__ void p1c_scatter(const int* __restrict__ row, const int* __restrict__ col,
                            const float* __restrict__ vals, int E, int NB,
                            const int* __restrict__ counts, const int* __restrict__ bucketStart,
                            int2* __restrict__ bdata) {
    __shared__ int cur[MAXNB];
    int blk = blockIdx.x;
    for (int b = threadIdx.x; b < NB; b += 256)
        cur[b] = bucketStart[b] + counts[(size_t)blk * NB + b];
    __syncthreads();
    int base = blk * CHUNK;
    int end = min(base + CHUNK, E);
    int vend = base + ((end - base) & ~3);
    for (int i = base + threadIdx.x * 4; i < vend; i += 1024) {
        int4 r = *(const int4*)(row + i);
        int4 c = *(const int4*)(col + i);
        float4 v = *(const float4*)(vals + i);
        int p0 = atomicAdd(&cur[r.x >> BSHIFT], 1);
        int p1 = atomicAdd(&cur[r.y >> BSHIFT], 1);
        int p2 = atomicAdd(&cur[r.z >> BSHIFT], 1);
        int p3 = atomicAdd(&cur[r.w >> BSHIFT], 1);
        bdata[p0] = make_int2(((r.x & (RPB - 1)) << 20) | c.x, __float_as_int(v.x));
        bdata[p1] = make_int2(((r.y & (RPB - 1)) << 20) | c.y, __float_as_int(v.y));
        bdata[p2] = make_int2(((r.z & (RPB - 1)) << 20) | c.z, __float_as_int(v.z));
        bdata[p3] = make_int2(((r.w & (RPB - 1)) << 20) | c.w, __float_as_int(v.w));
    }
    for (int i = vend + threadIdx.x; i < end; i += 256) {
        int r = row[i];
        int p = atomicAdd(&cur[r >> BSHIFT], 1);
        bdata[p] = make_int2(((r & (RPB - 1)) << 20) | col[i], __float_as_int(vals[i]));
    }
}

// P2: per-bucket regroup by exact row into PADDED rows (pads = colOff 0, val 0).
// pairs.x stores col*128 (byte offset). Only pad slots are filled post-scatter.
__global__ void p2_group(const int2* __restrict__ bdata, const int* __restrict__ bucketStart,
                         int NB, int N, int padSlop,
                         int* __restrict__ rowStart, int* __restrict__ rowLen,
                         int2* __restrict__ pairs) {
    __shared__ int hist[RPB];
    __shared__ int sh[256];
    __shared__ int cur[RPB];
    int b = blockIdx.x, t = threadIdx.x;
    int s0 = bucketStart[b], s1 = bucketStart[b + 1];
    int pbase = s0 + b * padSlop;
    for (int i = t; i < RPB; i += 256) hist[i] = 0;
    __syncthreads();
    for (int i = s0 + t; i < s1; i += 256)
        atomicAdd(&hist[(bdata[i].x >> 20) & (RPB - 1)], 1);
    __syncthreads();
    int v[4];
    int run = 0;
#pragma unroll
    for (int i = 0; i < 4; i++) {
        int h = hist[t * 4 + i];
        int hp = (h + PADMASK) & ~PADMASK;
        v[i] = run;  // exclusive within thread
        run += hp;
    }
    int inc = blockScan256(run, sh);
    int excl = inc - run;
#pragma unroll
    for (int i = 0; i < 4; i++) {
        int r = (b << BSHIFT) + t * 4 + i;
        int st = excl + v[i];
        if (r < N) {
            int h = hist[t * 4 + i];
            rowStart[r] = pbase + st;
            rowLen[r] = (h + PADMASK) & ~PADMASK;
        }
        cur[t * 4 + i] = st;
    }
    __syncthreads();
    // scatter real edges into row-grouped slots
    for (int i = s0 + t; i < s1; i += 256) {
        int2 e = bdata[i];
        int rl = (e.x >> 20) & (RPB - 1);
        int pos = atomicAdd(&cur[rl], 1);
        pairs[pbase + pos] = make_int2((e.x & 0xFFFFF) << 7, e.y);
    }
    __syncthreads();
    // fill ONLY the pad slots (colOff=0 -> row 0, val=0)
#pragma unroll
    for (int i = 0; i < 4; i++) {
        int h = hist[t * 4 + i];
        int hp = (h + PADMASK) & ~PADMASK;
        int st = excl + v[i];
        for (int p = st + h; p < st + hp; p++)
            pairs[pbase + p] = make_int2(0, 0);
    }
}

// ---------------- layer-1 SpMM: wave per row, 8 edge-groups x 8 dim-octs ----------------

__global__ void spmm1_k(const unsigned short* __restrict__ emb16,
                        const int* __restrict__ rowStart, const int* __restrict__ rowLen,
                        const int2* __restrict__ pairs,
                        int n_total, unsigned short* __restrict__ e1) {
    int wave = (blockIdx.x * blockDim.x + threadIdx.x) >> 6;
    int lane = threadIdx.x & 63;
    if (wave >= n_total) return;
    int eg = lane >> 3, dp = lane & 7;   // 8 edge groups, 8 dim-octs
    unsigned off0 = dp * 16u;            // byte offset of this lane's 8 bf16 dims
    const char* base = (const char*)emb16;
    int len = rowLen[wave];
    const int2* pp = pairs + rowStart[wave];
    float4 aA0 = {0.f, 0.f, 0.f, 0.f}, aA1 = {0.f, 0.f, 0.f, 0.f};
    float4 aB0 = {0.f, 0.f, 0.f, 0.f}, aB1 = {0.f, 0.f, 0.f, 0.f};
    int k = 0;
    for (; k + 16 <= len; k += 16) {
        int4 q = *(const int4*)(pp + k + 2 * eg);   // edges k+2eg, k+2eg+1
        uint4 g0 = *(const uint4*)(base + ((unsigned)q.x + off0));
        uint4 g1 = *(const uint4*)(base + ((unsigned)q.z + off0));
        float v0 = __int_as_float(q.y), v1 = __int_as_float(q.w);
        float4 x0 = bf2f4(g0.x, g0.y), x1 = bf2f4(g0.z, g0.w);
        float4 y0 = bf2f4(g1.x, g1.y), y1 = bf2f4(g1.z, g1.w);
        aA0.x += v0 * x0.x; aA0.y += v0 * x0.y; aA0.z += v0 * x0.z; aA0.w += v0 * x0.w;
        aA1.x += v0 * x1.x; aA1.y += v0 * x1.y; aA1.z += v0 * x1.z; aA1.w += v0 * x1.w;
        aB0.x += v1 * y0.x; aB0.y += v1 * y0.y; aB0.z += v1 * y0.z; aB0.w += v1 * y0.w;
        aB1.x += v1 * y1.x; aB1.y += v1 * y1.y; aB1.z += v1 * y1.z; aB1.w += v1 * y1.w;
    }
    if (k < len) {  // one trailing 8-block: edge k+eg (one per group)
        int2 p = pp[k + eg];
        uint4 g0 = *(const uint4*)(base + ((unsigned)p.x + off0));
        float v0 = __int_as_float(p.y);
        float4 x0 = bf2f4(g0.x, g0.y), x1 = bf2f4(g0.z, g0.w);
        aA0.x += v0 * x0.x; aA0.y += v0 * x0.y; aA0.z += v0 * x0.z; aA0.w += v0 * x0.w;
        aA1.x += v0 * x1.x; aA1.y += v0 * x1.y; aA1.z += v0 * x1.z; aA1.w += v0 * x1.w;
    }
    float4 s0, s1;
    s0.x = aA0.x + aB0.x; s0.y = aA0.y + aB0.y; s0.z = aA0.z + aB0.z; s0.w = aA0.w + aB0.w;
    s1.x = aA1.x + aB1.x; s1.y = aA1.y + aB1.y; s1.z = aA1.z + aB1.z; s1.w = aA1.w + aB1.w;
#pragma unroll
    for (int m = 8; m <= 32; m <<= 1) {
        s0.x += __shfl_xor(s0.x, m); s0.y += __shfl_xor(s0.y, m);
        s0.z += __shfl_xor(s0.z, m); s0.w += __shfl_xor(s0.w, m);
        s1.x += __shfl_xor(s1.x, m); s1.y += __shfl_xor(s1.y, m);
        s1.z += __shfl_xor(s1.z, m); s1.w += __shfl_xor(s1.w, m);
    }
    if (eg == 0) {
        uint4 o;
        o.x = (unsigned)f2bf(s0.x) | ((unsigned)f2bf(s0.y) << 16);
        o.y = (unsigned)f2bf(s0.z) | ((unsigned)f2bf(s0.w) << 16);
        o.z = (unsigned)f2bf(s1.x) | ((unsigned)f2bf(s1.y) << 16);
        o.w = (unsigned)f2bf(s1.z) | ((unsigned)f2bf(s1.w) << 16);
        *(uint4*)(e1 + (size_t)wave * DIM + dp * 8) = o;
    }
}

// ---------------- fused layer-2 + gather + dot epilogue ----------------

__global__ void final_k(const float* __restrict__ emb_user, const float* __restrict__ emb_item,
                        int n_user, const unsigned short* __restrict__ e1,
                        const int* __restrict__ rowStart, const int* __restrict__ rowLen,
                        const int2* __restrict__ pairs,
                        const int* __restrict__ u_nodes, const int* __restrict__ p_nodes,
                        const int* __restrict__ n_nodes, int B, float* __restrict__ out) {
    int wave = (blockIdx.x * blockDim.x + threadIdx.x) >> 6;
    int lane = threadIdx.x & 63;
    if (wave >= B) return;
    int eg = lane >> 4, dp = lane & 15;
    unsigned off0 = dp * 8u;
    const char* base = (const char*)e1;
    int nid[3] = {u_nodes[wave], p_nodes[wave], n_nodes[wave]};
    float4 l[3];
#pragma unroll
    for (int j = 0; j < 3; j++) {
        int r = nid[j];
        const float* base0 = (r < n_user) ? (emb_user + (size_t)r * DIM)
                                          : (emb_item + (size_t)(r - n_user) * DIM);
        float4 acc = *(const float4*)(base0 + dp * 4);                       // layer0 f32
        float4 t1 = bf2f4(*(const uint2*)(e1 + (size_t)r * DIM + dp * 4));   // layer1
        acc.x += t1.x; acc.y += t1.y; acc.z += t1.z; acc.w += t1.w;
        int len = rowLen[r];
        const int2* pp = pairs + rowStart[r];
        float4 a0 = {0.f, 0.f, 0.f, 0.f}, a1 = {0.f, 0.f, 0.f, 0.f};
        float4 a2 = {0.f, 0.f, 0.f, 0.f}, a3 = {0.f, 0.f, 0.f, 0.f};
        int k = 0;
        for (; k + 16 <= len; k += 16) {
            int4 q0 = *(const int4*)(pp + k + 2 * eg);
            int4 q1 = *(const int4*)(pp + k + 8 + 2 * eg);
            uint2 g0 = *(const uint2*)(base + ((unsigned)q0.x + off0));
            uint2 g1 = *(const uint2*)(base + ((unsigned)q0.z + off0));
            uint2 g2 = *(const uint2*)(base + ((unsigned)q1.x + off0));
            uint2 g3 = *(const uint2*)(base + ((unsigned)q1.z + off0));
            float v0 = __int_as_float(q0.y), v1 = __int_as_float(q0.w);
            float v2 = __int_as_float(q1.y), v3 = __int_as_float(q1.w);
            float4 x0 = bf2f4(g0), x1 = bf2f4(g1), x2 = bf2f4(g2), x3 = bf2f4(g3);
            a0.x += v0 * x0.x; a0.y += v0 * x0.y; a0.z += v0 * x0.z; a0.w += v0 * x0.w;
            a1.x += v1 * x1.x; a1.y += v1 * x1.y; a1.z += v1 * x1.z; a1.w += v1 * x1.w;
            a2.x += v2 * x2.x; a2.y += v2 * x2.y; a2.z += v2 * x2.z; a2.w += v2 * x2.w;
            a3.x += v3 * x3.x; a3.y += v3 * x3.y; a3.z += v3 * x3.z; a3.w += v3 * x3.w;
        }
        for (; k < len; k += 8) {
            int4 q0 = *(const int4*)(pp + k + 2 * eg);
            uint2 g0 = *(const uint2*)(base + ((unsigned)q0.x + off0));
            uint2 g1 = *(const uint2*)(base + ((unsigned)q0.z + off0));
            float v0 = __int_as_float(q0.y), v1 = __int_as_float(q0.w);
            float4 x0 = bf2f4(g0), x1 = bf2f4(g1);
            a0.x += v0 * x0.x; a0.y += v0 * x0.y; a0.z += v0 * x0.z; a0.w += v0 * x0.w;
            a1.x += v1 * x1.x; a1.y += v1 * x1.y; a1.z += v1 * x1.z; a1.w += v1 * x1.w;
        }
        float4 s;
        s.x = (a0.x + a1.x) + (a2.x + a3.x);
        s.y = (a0.y + a1.y) + (a2.y + a3.y);
        s.z = (a0.z + a1.z) + (a2.z + a3.z);
        s.w = (a0.w + a1.w) + (a2.w + a3.w);
        s.x += __shfl_xor(s.x, 16); s.y += __shfl_xor(s.y, 16);
        s.z += __shfl_xor(s.z, 16); s.w += __shfl_xor(s.w, 16);
        s.x += __shfl_xor(s.x, 32); s.y += __shfl_xor(s.y, 32);
        s.z += __shfl_xor(s.z, 32); s.w += __shfl_xor(s.w, 32);
        l[j].x = (acc.x + s.x) * (1.0f / 3.0f);
        l[j].y = (acc.y + s.y) * (1.0f / 3.0f);
        l[j].z = (acc.z + s.z) * (1.0f / 3.0f);
        l[j].w = (acc.w + s.w) * (1.0f / 3.0f);
    }
    float ps = l[0].x * l[1].x + l[0].y * l[1].y + l[0].z * l[1].z + l[0].w * l[1].w;
    float ns = l[0].x * l[2].x + l[0].y * l[2].y + l[0].z * l[2].z + l[0].w * l[2].w;
    ps += __shfl_xor(ps, 1); ns += __shfl_xor(ns, 1);
    ps += __shfl_xor(ps, 2); ns += __shfl_xor(ns, 2);
    ps += __shfl_xor(ps, 4); ns += __shfl_xor(ns, 4);
    ps += __shfl_xor(ps, 8); ns += __shfl_xor(ns, 8);
    if (lane == 0) {
        out[wave] = ps;
        out[B + wave] = ns;
    }
}

extern "C" void kernel_launch(void* const* d_in, const int* in_sizes, int n_in,
                              void* d_out, int out_size, void* d_ws, size_t ws_size,
                              hipStream_t stream) {
    const float* emb_user = (const float*)d_in[0];
    const float* emb_item = (const float*)d_in[1];
    const float* gvals    = (const float*)d_in[2];
    const int*   grow     = (const int*)d_in[3];
    const int*   gcol     = (const int*)d_in[4];
    const int*   unodes   = (const int*)d_in[5];
    const int*   pnodes   = (const int*)d_in[6];
    const int*   nnodes   = (const int*)d_in[7];
    float* out = (float*)d_out;

    int n_user = in_sizes[0] / DIM;
    int n_item = in_sizes[1] / DIM;
    int N = n_user + n_item;
    int E = in_sizes[2];
    int B = in_sizes[5];
    int NB = (N + RPB - 1) >> BSHIFT;
    int NBLK = (E + CHUNK - 1) / CHUNK;
    int padSlop = RPB * PADMASK;

    char* ws = (char*)d_ws;
    size_t off = 0;
    auto alloc = [&](size_t bytes) -> void* {
        void* p = ws + off;
        off = (off + bytes + 255) & ~(size_t)255;
        return p;
    };
    size_t embBytes = (size_t)N * DIM * 2;
    size_t countsBytes = (size_t)NBLK * NB * 4;
    size_t regionBBytes = (size_t)E * 8 > embBytes ? (size_t)E * 8 : embBytes;
    size_t regionABytes = countsBytes > embBytes ? countsBytes : embBytes;
    size_t pairsBytes = ((size_t)E + (size_t)NB * padSlop) * 8;

    int*  rowStart    = (int*)alloc((size_t)N * 4);
    int*  rowLen      = (int*)alloc((size_t)N * 4);
    int*  bucketTotal = (int*)alloc((size_t)MAXNB * 4);
    int*  bucketStart = (int*)alloc((size_t)(MAXNB + 1) * 4);
    int2* pairs       = (int2*)alloc(pairsBytes);
    char* regionB = (char*)alloc(regionBBytes);
    int2*           bdata = (int2*)regionB;   // dead after p2
    unsigned short* emb16 = (unsigned short*)regionB;
    char* regionA = (char*)alloc(regionABytes);
    int*            counts = (int*)regionA;   // dead after p1c
    unsigned short* e1     = (unsigned short*)regionA;
    (void)n_in; (void)out_size; (void)ws_size;

    // CSR build via two-level counting sort (no global atomics)
    p1a_hist<<<NBLK, 256, 0, stream>>>(grow, E, NB, counts);
    p1b_scan<<<NB, 256, 0, stream>>>(counts, NBLK, NB, bucketTotal);
    p_scan_tot<<<1, 256, 0, stream>>>(bucketTotal, NB, bucketStart);
    p1c_scatter<<<NBLK, 256, 0, stream>>>(grow, gcol, gvals, E, NB, counts, bucketStart, bdata);
    p2_group<<<NB, 256, 0, stream>>>(bdata, bucketStart, NB, N, padSlop,
                                     rowStart, rowLen, pairs);

    // bf16 pack of embeddings (after p2: emb16 overlays dead bdata)
    conv2_k<<<2048, 256, 0, stream>>>(emb_user, emb_item, n_user * DIM, N * DIM, emb16);

    // layer-1 SpMM over all rows (e1 overlays dead counts)
    spmm1_k<<<(N + 3) / 4, 256, 0, stream>>>(emb16, rowStart, rowLen, pairs, N, e1);
    // fused layer-2 + gather + dots
    final_k<<<(B + 3) / 4, 256, 0, stream>>>(emb_user, emb_item, n_user, e1,
                                             rowStart, rowLen, pairs,
                                             unodes, pnodes, nnodes, B, out);
}

// Round 12
// 300.950 us; speedup vs baseline: 1.0676x; 1.0085x over previous
//
#include <hip/hip_runtime.h>

#define DIM 64
#define CHUNK 16384     // edges per partition block
#define MAXNB 512       // max coarse buckets (N <= 524288 with BSHIFT=10)
#define BSHIFT 10
#define RPB 1024        // rows per bucket (1 << BSHIFT)
#define PADMASK 7       // rows padded to multiple of 8

union H8 { uint4 u; _Float16 h[8]; };
union H4 { uint2 u; _Float16 h[4]; };

// inclusive block scan over 256 per-thread values; sh[255] = total after call
__device__ __forceinline__ int blockScan256(int v, int* sh) {
    int t = threadIdx.x;
    sh[t] = v;
    __syncthreads();
    for (int off = 1; off < 256; off <<= 1) {
        int x = (t >= off) ? sh[t - off] : 0;
        __syncthreads();
        sh[t] += x;
        __syncthreads();
    }
    return sh[t];
}

// ---------------- f32 -> packed f16 conversion (both tables, one launch) ----------------

__global__ void conv2_k(const float* __restrict__ u, const float* __restrict__ it,
                        int nu, int ntot, unsigned short* __restrict__ o) {
    int i = blockIdx.x * blockDim.x + threadIdx.x;
    int stride = gridDim.x * blockDim.x;
    int n8 = ntot >> 3;
    for (int t = i; t < n8; t += stride) {
        int e = t * 8;
        const float* src = (e < nu) ? (u + e) : (it + (e - nu));
        float4 x = *(const float4*)src;
        float4 y = *(const float4*)(src + 4);
        H8 v;
        v.h[0] = (_Float16)x.x; v.h[1] = (_Float16)x.y;
        v.h[2] = (_Float16)x.z; v.h[3] = (_Float16)x.w;
        v.h[4] = (_Float16)y.x; v.h[5] = (_Float16)y.y;
        v.h[6] = (_Float16)y.z; v.h[7] = (_Float16)y.w;
        ((uint4*)o)[t] = v.u;
    }
}

// ---------------- two-level counting sort (no global atomics) ----------------

__global__ void p1a_hist(const int* __restrict__ row, int E, int NB,
                         int* __restrict__ counts) {
    __shared__ int h[MAXNB];
    for (int b = threadIdx.x; b < NB; b += 256) h[b] = 0;
    __syncthreads();
    int base = blockIdx.x * CHUNK;
    int end = min(base + CHUNK, E);
    int vend = base + ((end - base) & ~3);
    for (int i = base + threadIdx.x * 4; i < vend; i += 1024) {
        int4 r = *(const int4*)(row + i);
        atomicAdd(&h[r.x >> BSHIFT], 1);
        atomicAdd(&h[r.y >> BSHIFT], 1);
        atomicAdd(&h[r.z >> BSHIFT], 1);
        atomicAdd(&h[r.w >> BSHIFT], 1);
    }
    for (int i = vend + threadIdx.x; i < end; i += 256) atomicAdd(&h[row[i] >> BSHIFT], 1);
    __syncthreads();
    int blk = blockIdx.x;
    for (int b = threadIdx.x; b < NB; b += 256) counts[(size_t)blk * NB + b] = h[b];
}

__global__ void p1b_scan(int* __restrict__ counts, int NBLK, int NB,
                         int* __restrict__ bucketTotal) {
    int b = blockIdx.x, t = threadIdx.x;
    __shared__ int sh[256];
    int v[8];
    int run = 0;
#pragma unroll
    for (int i = 0; i < 8; i++) {
        int idx = t * 8 + i;
        int c = (idx < NBLK) ? counts[(size_t)idx * NB + b] : 0;
        v[i] = run;  // exclusive within thread
        run += c;
    }
    int inc = blockScan256(run, sh);
    int excl = inc - run;
#pragma unroll
    for (int i = 0; i < 8; i++) {
        int idx = t * 8 + i;
        if (idx < NBLK) counts[(size_t)idx * NB + b] = v[i] + excl;
    }
    if (t == 255) bucketTotal[b] = sh[255];
}

__global__ void p_scan_tot(const int* __restrict__ bucketTotal, int NB,
                           int* __restrict__ bucketStart) {
    int t = threadIdx.x;
    __shared__ int sh[256];
    int v[8];
    int run = 0;
#pragma unroll
    for (int i = 0; i < 8; i++) {
        int idx = t * 8 + i;
        int c = (idx < NB) ? bucketTotal[idx] : 0;
        v[i] = run;
        run += c;
    }
    int inc = blockScan256(run, sh);
    int excl = inc - run;
#pragma unroll
    for (int i = 0; i < 8; i++) {
        int idx = t * 8 + i;
        if (idx < NB) bucketStart[idx] = v[i] + excl;
    }
    if (t == 255) bucketStart[NB] = sh[255];
}

__global__ void p1c_scatter(const int* __restrict__ row, const int* __restrict__ col,
                            const float* __restrict__ vals, int E, int NB,
                            const int* __restrict__ counts, const int* __restrict__ bucketStart,
                            int2* __restrict__ bdata) {
    __shared__ int cur[MAXNB];
    int blk = blockIdx.x;
    for (int b = threadIdx.x; b < NB; b += 256)
        cur[b] = bucketStart[b] + counts[(size_t)blk * NB + b];
    __syncthreads();
    int base = blk * CHUNK;
    int end = min(base + CHUNK, E);
    int vend = base + ((end - base) & ~3);
    for (int i = base + threadIdx.x * 4; i < vend; i += 1024) {
        int4 r = *(const int4*)(row + i);
        int4 c = *(const int4*)(col + i);
        float4 v = *(const float4*)(vals + i);
        int p0 = atomicAdd(&cur[r.x >> BSHIFT], 1);
        int p1 = atomicAdd(&cur[r.y >> BSHIFT], 1);
        int p2 = atomicAdd(&cur[r.z >> BSHIFT], 1);
        int p3 = atomicAdd(&cur[r.w >> BSHIFT], 1);
        bdata[p0] = make_int2(((r.x & (RPB - 1)) << 20) | c.x, __float_as_int(v.x));
        bdata[p1] = make_int2(((r.y & (RPB - 1)) << 20) | c.y, __float_as_int(v.y));
        bdata[p2] = make_int2(((r.z & (RPB - 1)) << 20) | c.z, __float_as_int(v.z));
        bdata[p3] = make_int2(((r.w & (RPB - 1)) << 20) | c.w, __float_as_int(v.w));
    }
    for (int i = vend + threadIdx.x; i < end; i += 256) {
        int r = row[i];
        int p = atomicAdd(&cur[r >> BSHIFT], 1);
        bdata[p] = make_int2(((r & (RPB - 1)) << 20) | col[i], __float_as_int(vals[i]));
    }
}

// P2: per-bucket regroup by exact row into PADDED rows (pads = colOff 0, val 0).
// pairs.x stores col*128 (byte offset). Only pad slots are filled post-scatter.
__global__ void p2_group(const int2* __restrict__ bdata, const int* __restrict__ bucketStart,
                         int NB, int N, int padSlop,
                         int* __restrict__ rowStart, int* __restrict__ rowLen,
                         int2* __restrict__ pairs) {
    __shared__ int hist[RPB];
    __shared__ int sh[256];
    __shared__ int cur[RPB];
    int b = blockIdx.x, t = threadIdx.x;
    int s0 = bucketStart[b], s1 = bucketStart[b + 1];
    int pbase = s0 + b * padSlop;
    for (int i = t; i < RPB; i += 256) hist[i] = 0;
    __syncthreads();
    for (int i = s0 + t; i < s1; i += 256)
        atomicAdd(&hist[(bdata[i].x >> 20) & (RPB - 1)], 1);
    __syncthreads();
    int v[4];
    int run = 0;
#pragma unroll
    for (int i = 0; i < 4; i++) {
        int h = hist[t * 4 + i];
        int hp = (h + PADMASK) & ~PADMASK;
        v[i] = run;  // exclusive within thread
        run += hp;
    }
    int inc = blockScan256(run, sh);
    int excl = inc - run;
#pragma unroll
    for (int i = 0; i < 4; i++) {
        int r = (b << BSHIFT) + t * 4 + i;
        int st = excl + v[i];
        if (r < N) {
            int h = hist[t * 4 + i];
            rowStart[r] = pbase + st;
            rowLen[r] = (h + PADMASK) & ~PADMASK;
        }
        cur[t * 4 + i] = st;
    }
    __syncthreads();
    // scatter real edges into row-grouped slots
    for (int i = s0 + t; i < s1; i += 256) {
        int2 e = bdata[i];
        int rl = (e.x >> 20) & (RPB - 1);
        int pos = atomicAdd(&cur[rl], 1);
        pairs[pbase + pos] = make_int2((e.x & 0xFFFFF) << 7, e.y);
    }
    __syncthreads();
    // fill ONLY the pad slots (colOff=0 -> row 0, val=0)
#pragma unroll
    for (int i = 0; i < 4; i++) {
        int h = hist[t * 4 + i];
        int hp = (h + PADMASK) & ~PADMASK;
        int st = excl + v[i];
        for (int p = st + h; p < st + hp; p++)
            pairs[pbase + p] = make_int2(0, 0);
    }
}

// ---------------- layer-1 SpMM: wave per row, 8 edge-groups x 8 dim-octs ----------------
// f16 storage + (float)h * v accumulation -> compiler emits v_fma_mix_f32 (no unpack ops).

__global__ void spmm1_k(const unsigned short* __restrict__ emb16,
                        const int* __restrict__ rowStart, const int* __restrict__ rowLen,
                        const int2* __restrict__ pairs,
                        int n_total, unsigned short* __restrict__ e1) {
    int wave = (blockIdx.x * blockDim.x + threadIdx.x) >> 6;
    int lane = threadIdx.x & 63;
    if (wave >= n_total) return;
    int eg = lane >> 3, dp = lane & 7;   // 8 edge groups, 8 dim-octs
    unsigned off0 = dp * 16u;            // byte offset of this lane's 8 f16 dims
    const char* base = (const char*)emb16;
    int len = rowLen[wave];
    const int2* pp = pairs + rowStart[wave];
    float aA[8] = {0.f, 0.f, 0.f, 0.f, 0.f, 0.f, 0.f, 0.f};
    float aB[8] = {0.f, 0.f, 0.f, 0.f, 0.f, 0.f, 0.f, 0.f};
    int k = 0;
    for (; k + 16 <= len; k += 16) {
        int4 q = *(const int4*)(pp + k + 2 * eg);   // edges k+2eg, k+2eg+1
        H8 g0, g1;
        g0.u = *(const uint4*)(base + ((unsigned)q.x + off0));
        g1.u = *(const uint4*)(base + ((unsigned)q.z + off0));
        float v0 = __int_as_float(q.y), v1 = __int_as_float(q.w);
#pragma unroll
        for (int i = 0; i < 8; i++) aA[i] += (float)g0.h[i] * v0;
#pragma unroll
        for (int i = 0; i < 8; i++) aB[i] += (float)g1.h[i] * v1;
    }
    if (k < len) {  // one trailing 8-block: edge k+eg (one per group)
        int2 p = pp[k + eg];
        H8 g0;
        g0.u = *(const uint4*)(base + ((unsigned)p.x + off0));
        float v0 = __int_as_float(p.y);
#pragma unroll
        for (int i = 0; i < 8; i++) aA[i] += (float)g0.h[i] * v0;
    }
    float s[8];
#pragma unroll
    for (int i = 0; i < 8; i++) s[i] = aA[i] + aB[i];
#pragma unroll
    for (int m = 8; m <= 32; m <<= 1) {
#pragma unroll
        for (int i = 0; i < 8; i++) s[i] += __shfl_xor(s[i], m);
    }
    if (eg == 0) {
        H8 o;
#pragma unroll
        for (int i = 0; i < 8; i++) o.h[i] = (_Float16)s[i];
        *(uint4*)(e1 + (size_t)wave * DIM + dp * 8) = o.u;
    }
}

// ---------------- fused layer-2 + gather + dot epilogue ----------------

__global__ void final_k(const float* __restrict__ emb_user, const float* __restrict__ emb_item,
                        int n_user, const unsigned short* __restrict__ e1,
                        const int* __restrict__ rowStart, const int* __restrict__ rowLen,
                        const int2* __restrict__ pairs,
                        const int* __restrict__ u_nodes, const int* __restrict__ p_nodes,
                        const int* __restrict__ n_nodes, int B, float* __restrict__ out) {
    int wave = (blockIdx.x * blockDim.x + threadIdx.x) >> 6;
    int lane = threadIdx.x & 63;
    if (wave >= B) return;
    int eg = lane >> 4, dp = lane & 15;
    unsigned off0 = dp * 8u;
    const char* base = (const char*)e1;
    int nid[3] = {u_nodes[wave], p_nodes[wave], n_nodes[wave]};
    float l[3][4];
#pragma unroll
    for (int j = 0; j < 3; j++) {
        int r = nid[j];
        const float* base0 = (r < n_user) ? (emb_user + (size_t)r * DIM)
                                          : (emb_item + (size_t)(r - n_user) * DIM);
        float4 l0 = *(const float4*)(base0 + dp * 4);                 // layer0 f32
        H4 t1;
        t1.u = *(const uint2*)(e1 + (size_t)r * DIM + dp * 4);        // layer1 f16
        float acc[4];
        acc[0] = l0.x + (float)t1.h[0];
        acc[1] = l0.y + (float)t1.h[1];
        acc[2] = l0.z + (float)t1.h[2];
        acc[3] = l0.w + (float)t1.h[3];
        int len = rowLen[r];
        const int2* pp = pairs + rowStart[r];
        float a0[4] = {0.f, 0.f, 0.f, 0.f}, a1[4] = {0.f, 0.f, 0.f, 0.f};
        float a2[4] = {0.f, 0.f, 0.f, 0.f}, a3[4] = {0.f, 0.f, 0.f, 0.f};
        int k = 0;
        for (; k + 16 <= len; k += 16) {
            int4 q0 = *(const int4*)(pp + k + 2 * eg);
            int4 q1 = *(const int4*)(pp + k + 8 + 2 * eg);
            H4 g0, g1, g2, g3;
            g0.u = *(const uint2*)(base + ((unsigned)q0.x + off0));
            g1.u = *(const uint2*)(base + ((unsigned)q0.z + off0));
            g2.u = *(const uint2*)(base + ((unsigned)q1.x + off0));
            g3.u = *(const uint2*)(base + ((unsigned)q1.z + off0));
            float v0 = __int_as_float(q0.y), v1 = __int_as_float(q0.w);
            float v2 = __int_as_float(q1.y), v3 = __int_as_float(q1.w);
#pragma unroll
            for (int i = 0; i < 4; i++) {
                a0[i] += (float)g0.h[i] * v0;
                a1[i] += (float)g1.h[i] * v1;
                a2[i] += (float)g2.h[i] * v2;
                a3[i] += (float)g3.h[i] * v3;
            }
        }
        for (; k < len; k += 8) {
            int4 q0 = *(const int4*)(pp + k + 2 * eg);
            H4 g0, g1;
            g0.u = *(const uint2*)(base + ((unsigned)q0.x + off0));
            g1.u = *(const uint2*)(base + ((unsigned)q0.z + off0));
            float v0 = __int_as_float(q0.y), v1 = __int_as_float(q0.w);
#pragma unroll
            for (int i = 0; i < 4; i++) {
                a0[i] += (float)g0.h[i] * v0;
                a1[i] += (float)g1.h[i] * v1;
            }
        }
        float s[4];
#pragma unroll
        for (int i = 0; i < 4; i++) s[i] = (a0[i] + a1[i]) + (a2[i] + a3[i]);
#pragma unroll
        for (int i = 0; i < 4; i++) {
            s[i] += __shfl_xor(s[i], 16);
            s[i] += __shfl_xor(s[i], 32);
        }
#pragma unroll
        for (int i = 0; i < 4; i++) l[j][i] = (acc[i] + s[i]) * (1.0f / 3.0f);
    }
    float ps = l[0][0] * l[1][0] + l[0][1] * l[1][1] + l[0][2] * l[1][2] + l[0][3] * l[1][3];
    float ns = l[0][0] * l[2][0] + l[0][1] * l[2][1] + l[0][2] * l[2][2] + l[0][3] * l[2][3];
    ps += __shfl_xor(ps, 1); ns += __shfl_xor(ns, 1);
    ps += __shfl_xor(ps, 2); ns += __shfl_xor(ns, 2);
    ps += __shfl_xor(ps, 4); ns += __shfl_xor(ns, 4);
    ps += __shfl_xor(ps, 8); ns += __shfl_xor(ns, 8);
    if (lane == 0) {
        out[wave] = ps;
        out[B + wave] = ns;
    }
}

extern "C" void kernel_launch(void* const* d_in, const int* in_sizes, int n_in,
                              void* d_out, int out_size, void* d_ws, size_t ws_size,
                              hipStream_t stream) {
    const float* emb_user = (const float*)d_in[0];
    const float* emb_item = (const float*)d_in[1];
    const float* gvals    = (const float*)d_in[2];
    const int*   grow     = (const int*)d_in[3];
    const int*   gcol     = (const int*)d_in[4];
    const int*   unodes   = (const int*)d_in[5];
    const int*   pnodes   = (const int*)d_in[6];
    const int*   nnodes   = (const int*)d_in[7];
    float* out = (float*)d_out;

    int n_user = in_sizes[0] / DIM;
    int n_item = in_sizes[1] / DIM;
    int N = n_user + n_item;
    int E = in_sizes[2];
    int B = in_sizes[5];
    int NB = (N + RPB - 1) >> BSHIFT;
    int NBLK = (E + CHUNK - 1) / CHUNK;
    int padSlop = RPB * PADMASK;

    char* ws = (char*)d_ws;
    size_t off = 0;
    auto alloc = [&](size_t bytes) -> void* {
        void* p = ws + off;
        off = (off + bytes + 255) & ~(size_t)255;
        return p;
    };
    size_t embBytes = (size_t)N * DIM * 2;
    size_t countsBytes = (size_t)NBLK * NB * 4;
    size_t regionBBytes = (size_t)E * 8 > embBytes ? (size_t)E * 8 : embBytes;
    size_t regionABytes = countsBytes > embBytes ? countsBytes : embBytes;
    size_t pairsBytes = ((size_t)E + (size_t)NB * padSlop) * 8;

    int*  rowStart    = (int*)alloc((size_t)N * 4);
    int*  rowLen      = (int*)alloc((size_t)N * 4);
    int*  bucketTotal = (int*)alloc((size_t)MAXNB * 4);
    int*  bucketStart = (int*)alloc((size_t)(MAXNB + 1) * 4);
    int2* pairs       = (int2*)alloc(pairsBytes);
    char* regionB = (char*)alloc(regionBBytes);
    int2*           bdata = (int2*)regionB;   // dead after p2
    unsigned short* emb16 = (unsigned short*)regionB;
    char* regionA = (char*)alloc(regionABytes);
    int*            counts = (int*)regionA;   // dead after p1c
    unsigned short* e1     = (unsigned short*)regionA;
    (void)n_in; (void)out_size; (void)ws_size;

    // CSR build via two-level counting sort (no global atomics)
    p1a_hist<<<NBLK, 256, 0, stream>>>(grow, E, NB, counts);
    p1b_scan<<<NB, 256, 0, stream>>>(counts, NBLK, NB, bucketTotal);
    p_scan_tot<<<1, 256, 0, stream>>>(bucketTotal, NB, bucketStart);
    p1c_scatter<<<NBLK, 256, 0, stream>>>(grow, gcol, gvals, E, NB, counts, bucketStart, bdata);
    p2_group<<<NB, 256, 0, stream>>>(bdata, bucketStart, NB, N, padSlop,
                                     rowStart, rowLen, pairs);

    // f16 pack of embeddings (after p2: emb16 overlays dead bdata)
    conv2_k<<<2048, 256, 0, stream>>>(emb_user, emb_item, n_user * DIM, N * DIM, emb16);

    // layer-1 SpMM over all rows (e1 overlays dead counts)
    spmm1_k<<<(N + 3) / 4, 256, 0, stream>>>(emb16, rowStart, rowLen, pairs, N, e1);
    // fused layer-2 + gather + dots
    final_k<<<(B + 3) / 4, 256, 0, stream>>>(emb_user, emb_item, n_user, e1,
                                             rowStart, rowLen, pairs,
                                             unodes, pnodes, nnodes, B, out);
}

// Round 13
// 293.016 us; speedup vs baseline: 1.0965x; 1.0271x over previous
//
#include <hip/hip_runtime.h>

#define DIM 64
#define CHUNK 8192      // edges per partition block (64KB LDS stage in p1c)
#define MAXNB 512       // max coarse buckets (N <= 524288 with BSHIFT=10)
#define BSHIFT 10
#define RPB 1024        // rows per bucket (1 << BSHIFT)
#define PADMASK 7       // rows padded to multiple of 8
#define CONVB 768       // conv blocks appended to p1a grid (sepEmb mode)

union H8 { uint4 u; _Float16 h[8]; };
union H4 { uint2 u; _Float16 h[4]; };

// inclusive block scan over 256 per-thread values; sh[255] = total after call
__device__ __forceinline__ int blockScan256(int v, int* sh) {
    int t = threadIdx.x;
    sh[t] = v;
    __syncthreads();
    for (int off = 1; off < 256; off <<= 1) {
        int x = (t >= off) ? sh[t - off] : 0;
        __syncthreads();
        sh[t] += x;
        __syncthreads();
    }
    return sh[t];
}

__device__ __forceinline__ void convBody(const float* __restrict__ u,
                                         const float* __restrict__ it,
                                         int nu, int ntot, unsigned short* __restrict__ o,
                                         int start, int stride) {
    int n8 = ntot >> 3;
    for (int t = start; t < n8; t += stride) {
        int e = t * 8;
        const float* src = (e < nu) ? (u + e) : (it + (e - nu));
        float4 x = *(const float4*)src;
        float4 y = *(const float4*)(src + 4);
        H8 v;
        v.h[0] = (_Float16)x.x; v.h[1] = (_Float16)x.y;
        v.h[2] = (_Float16)x.z; v.h[3] = (_Float16)x.w;
        v.h[4] = (_Float16)y.x; v.h[5] = (_Float16)y.y;
        v.h[6] = (_Float16)y.z; v.h[7] = (_Float16)y.w;
        ((uint4*)o)[t] = v.u;
    }
}

// ---------------- P1a (coarse hist) + fused f32->f16 conv (sepEmb mode) ----------------

__global__ void p1a_conv(const int* __restrict__ row, int E, int NB,
                         int* __restrict__ counts,
                         const float* __restrict__ u, const float* __restrict__ it,
                         int nu, int ntot, unsigned short* __restrict__ o, int NBLK) {
    __shared__ int h[MAXNB];
    int blk = blockIdx.x;
    if (blk < NBLK) {
        for (int b = threadIdx.x; b < NB; b += 256) h[b] = 0;
        __syncthreads();
        int base = blk * CHUNK;
        int end = min(base + CHUNK, E);
        int vend = base + ((end - base) & ~3);
        for (int i = base + threadIdx.x * 4; i < vend; i += 1024) {
            int4 r = *(const int4*)(row + i);
            atomicAdd(&h[r.x >> BSHIFT], 1);
            atomicAdd(&h[r.y >> BSHIFT], 1);
            atomicAdd(&h[r.z >> BSHIFT], 1);
            atomicAdd(&h[r.w >> BSHIFT], 1);
        }
        for (int i = vend + threadIdx.x; i < end; i += 256) atomicAdd(&h[row[i] >> BSHIFT], 1);
        __syncthreads();
        for (int b = threadIdx.x; b < NB; b += 256) counts[(size_t)blk * NB + b] = h[b];
    } else {
        int nConv = gridDim.x - NBLK;
        convBody(u, it, nu, ntot, o, (blk - NBLK) * 256 + threadIdx.x, nConv * 256);
    }
}

// fallback standalone conv (overlay layout)
__global__ void conv2_k(const float* __restrict__ u, const float* __restrict__ it,
                        int nu, int ntot, unsigned short* __restrict__ o) {
    convBody(u, it, nu, ntot, o, blockIdx.x * blockDim.x + threadIdx.x,
             gridDim.x * blockDim.x);
}

__global__ void p1b_scan(int* __restrict__ counts, int NBLK, int NB,
                         int* __restrict__ bucketTotal) {
    int b = blockIdx.x, t = threadIdx.x;
    __shared__ int sh[256];
    int v[8];
    int run = 0;
#pragma unroll
    for (int i = 0; i < 8; i++) {
        int idx = t * 8 + i;
        int c = (idx < NBLK) ? counts[(size_t)idx * NB + b] : 0;
        v[i] = run;  // exclusive within thread
        run += c;
    }
    int inc = blockScan256(run, sh);
    int excl = inc - run;
#pragma unroll
    for (int i = 0; i < 8; i++) {
        int idx = t * 8 + i;
        if (idx < NBLK) counts[(size_t)idx * NB + b] = v[i] + excl;
    }
    if (t == 255) bucketTotal[b] = sh[255];
}

__global__ void p_scan_tot(const int* __restrict__ bucketTotal, int NB,
                           int* __restrict__ bucketStart) {
    int t = threadIdx.x;
    __shared__ int sh[256];
    int v[8];
    int run = 0;
#pragma unroll
    for (int i = 0; i < 8; i++) {
        int idx = t * 8 + i;
        int c = (idx < NB) ? bucketTotal[idx] : 0;
        v[i] = run;
        run += c;
    }
    int inc = blockScan256(run, sh);
    int excl = inc - run;
#pragma unroll
    for (int i = 0; i < 8; i++) {
        int idx = t * 8 + i;
        if (idx < NB) bucketStart[idx] = v[i] + excl;
    }
    if (t == 255) bucketStart[NB] = sh[255];
}

// P1c: scatter into 64KB LDS stage grouped by bucket, then COALESCED writeback of
// each bucket's contiguous run. Raw per-(chunk,bucket) counts recovered from the
// scanned counts matrix: raw = counts[blk+1][b] - counts[blk][b] (last: bucketTotal).
__global__ void p1c_scatter(const int* __restrict__ row, const int* __restrict__ col,
                            const float* __restrict__ vals, int E, int NB, int NBLK,
                            const int* __restrict__ counts, const int* __restrict__ bucketTotal,
                            const int* __restrict__ bucketStart, int2* __restrict__ bdata) {
    __shared__ int2 stage[CHUNK];
    __shared__ int cur[MAXNB];
    __shared__ int rawcnt[MAXNB];
    __shared__ int sh[256];
    int blk = blockIdx.x, t = threadIdx.x;
    int base = blk * CHUNK;
    int end = min(base + CHUNK, E);
    // local exclusive scan of raw counts -> stage offsets
    int v[2];
    int run = 0;
#pragma unroll
    for (int i = 0; i < 2; i++) {
        int b = t * 2 + i;
        int c = 0;
        if (b < NB) {
            int s0 = counts[(size_t)blk * NB + b];
            int s1 = (blk + 1 < NBLK) ? counts[(size_t)(blk + 1) * NB + b] : bucketTotal[b];
            c = s1 - s0;
            rawcnt[b] = c;
        }
        v[i] = run;
        run += c;
    }
    int inc = blockScan256(run, sh);
    int excl = inc - run;
#pragma unroll
    for (int i = 0; i < 2; i++) {
        int b = t * 2 + i;
        if (b < NB) cur[b] = excl + v[i];
    }
    __syncthreads();
    // scatter edges into the LDS stage (bucket-grouped)
    int vend = base + ((end - base) & ~3);
    for (int i = base + t * 4; i < vend; i += 1024) {
        int4 r = *(const int4*)(row + i);
        int4 c = *(const int4*)(col + i);
        float4 w = *(const float4*)(vals + i);
        int p0 = atomicAdd(&cur[r.x >> BSHIFT], 1);
        int p1 = atomicAdd(&cur[r.y >> BSHIFT], 1);
        int p2 = atomicAdd(&cur[r.z >> BSHIFT], 1);
        int p3 = atomicAdd(&cur[r.w >> BSHIFT], 1);
        stage[p0] = make_int2(((r.x & (RPB - 1)) << 20) | c.x, __float_as_int(w.x));
        stage[p1] = make_int2(((r.y & (RPB - 1)) << 20) | c.y, __float_as_int(w.y));
        stage[p2] = make_int2(((r.z & (RPB - 1)) << 20) | c.z, __float_as_int(w.z));
        stage[p3] = make_int2(((r.w & (RPB - 1)) << 20) | c.w, __float_as_int(w.w));
    }
    for (int i = vend + t; i < end; i += 256) {
        int r = row[i];
        int p = atomicAdd(&cur[r >> BSHIFT], 1);
        stage[p] = make_int2(((r & (RPB - 1)) << 20) | col[i], __float_as_int(vals[i]));
    }
    __syncthreads();
    // coalesced writeback: wave per bucket round-robin; each bucket is one
    // contiguous run both in LDS and in global.
    int wv = t >> 6, lane = t & 63;
    for (int b = wv; b < NB; b += 4) {
        int cnt = rawcnt[b];
        int lo = cur[b] - cnt;
        int gb = bucketStart[b] + counts[(size_t)blk * NB + b];
        for (int i = lane; i < cnt; i += 64)
            bdata[gb + i] = stage[lo + i];
    }
}

// P2: per-bucket regroup by exact row into PADDED rows (pads = colOff 0, val 0).
// pairs.x stores col*128 (byte offset). Only pad slots are filled post-scatter.
__global__ void p2_group(const int2* __restrict__ bdata, const int* __restrict__ bucketStart,
                         int NB, int N, int padSlop,
                         int* __restrict__ rowStart, int* __restrict__ rowLen,
                         int2* __restrict__ pairs) {
    __shared__ int hist[RPB];
    __shared__ int sh[256];
    __shared__ int cur[RPB];
    int b = blockIdx.x, t = threadIdx.x;
    int s0 = bucketStart[b], s1 = bucketStart[b + 1];
    int pbase = s0 + b * padSlop;
    for (int i = t; i < RPB; i += 256) hist[i] = 0;
    __syncthreads();
    for (int i = s0 + t; i < s1; i += 256)
        atomicAdd(&hist[(bdata[i].x >> 20) & (RPB - 1)], 1);
    __syncthreads();
    int v[4];
    int run = 0;
#pragma unroll
    for (int i = 0; i < 4; i++) {
        int h = hist[t * 4 + i];
        int hp = (h + PADMASK) & ~PADMASK;
        v[i] = run;  // exclusive within thread
        run += hp;
    }
    int inc = blockScan256(run, sh);
    int excl = inc - run;
#pragma unroll
    for (int i = 0; i < 4; i++) {
        int r = (b << BSHIFT) + t * 4 + i;
        int st = excl + v[i];
        if (r < N) {
            int h = hist[t * 4 + i];
            rowStart[r] = pbase + st;
            rowLen[r] = (h + PADMASK) & ~PADMASK;
        }
        cur[t * 4 + i] = st;
    }
    __syncthreads();
    for (int i = s0 + t; i < s1; i += 256) {
        int2 e = bdata[i];
        int rl = (e.x >> 20) & (RPB - 1);
        int pos = atomicAdd(&cur[rl], 1);
        pairs[pbase + pos] = make_int2((e.x & 0xFFFFF) << 7, e.y);
    }
    __syncthreads();
#pragma unroll
    for (int i = 0; i < 4; i++) {
        int h = hist[t * 4 + i];
        int hp = (h + PADMASK) & ~PADMASK;
        int st = excl + v[i];
        for (int p = st + h; p < st + hp; p++)
            pairs[pbase + p] = make_int2(0, 0);
    }
}

// ---------------- layer-1 SpMM: wave per row, 8 edge-groups x 8 dim-octs ----------------
// f16 storage + (float)h * v accumulation -> v_fma_mix_f32 (no unpack ops).

__global__ void spmm1_k(const unsigned short* __restrict__ emb16,
                        const int* __restrict__ rowStart, const int* __restrict__ rowLen,
                        const int2* __restrict__ pairs,
                        int n_total, unsigned short* __restrict__ e1) {
    int wave = (blockIdx.x * blockDim.x + threadIdx.x) >> 6;
    int lane = threadIdx.x & 63;
    if (wave >= n_total) return;
    int eg = lane >> 3, dp = lane & 7;
    unsigned off0 = dp * 16u;
    const char* base = (const char*)emb16;
    int len = rowLen[wave];
    const int2* pp = pairs + rowStart[wave];
    float aA[8] = {0.f, 0.f, 0.f, 0.f, 0.f, 0.f, 0.f, 0.f};
    float aB[8] = {0.f, 0.f, 0.f, 0.f, 0.f, 0.f, 0.f, 0.f};
    int k = 0;
    for (; k + 16 <= len; k += 16) {
        int4 q = *(const int4*)(pp + k + 2 * eg);
        H8 g0, g1;
        g0.u = *(const uint4*)(base + ((unsigned)q.x + off0));
        g1.u = *(const uint4*)(base + ((unsigned)q.z + off0));
        float v0 = __int_as_float(q.y), v1 = __int_as_float(q.w);
#pragma unroll
        for (int i = 0; i < 8; i++) aA[i] += (float)g0.h[i] * v0;
#pragma unroll
        for (int i = 0; i < 8; i++) aB[i] += (float)g1.h[i] * v1;
    }
    if (k < len) {
        int2 p = pp[k + eg];
        H8 g0;
        g0.u = *(const uint4*)(base + ((unsigned)p.x + off0));
        float v0 = __int_as_float(p.y);
#pragma unroll
        for (int i = 0; i < 8; i++) aA[i] += (float)g0.h[i] * v0;
    }
    float s[8];
#pragma unroll
    for (int i = 0; i < 8; i++) s[i] = aA[i] + aB[i];
#pragma unroll
    for (int m = 8; m <= 32; m <<= 1) {
#pragma unroll
        for (int i = 0; i < 8; i++) s[i] += __shfl_xor(s[i], m);
    }
    if (eg == 0) {
        H8 o;
#pragma unroll
        for (int i = 0; i < 8; i++) o.h[i] = (_Float16)s[i];
        *(uint4*)(e1 + (size_t)wave * DIM + dp * 8) = o.u;
    }
}

// ---------------- fused layer-2 + gather + dot epilogue ----------------

__global__ void final_k(const float* __restrict__ emb_user, const float* __restrict__ emb_item,
                        int n_user, const unsigned short* __restrict__ e1,
                        const int* __restrict__ rowStart, const int* __restrict__ rowLen,
                        const int2* __restrict__ pairs,
                        const int* __restrict__ u_nodes, const int* __restrict__ p_nodes,
                        const int* __restrict__ n_nodes, int B, float* __restrict__ out) {
    int wave = (blockIdx.x * blockDim.x + threadIdx.x) >> 6;
    int lane = threadIdx.x & 63;
    if (wave >= B) return;
    int eg = lane >> 4, dp = lane & 15;
    unsigned off0 = dp * 8u;
    const char* base = (const char*)e1;
    int nid[3] = {u_nodes[wave], p_nodes[wave], n_nodes[wave]};
    float l[3][4];
#pragma unroll
    for (int j = 0; j < 3; j++) {
        int r = nid[j];
        const float* base0 = (r < n_user) ? (emb_user + (size_t)r * DIM)
                                          : (emb_item + (size_t)(r - n_user) * DIM);
        float4 l0 = *(const float4*)(base0 + dp * 4);
        H4 t1;
        t1.u = *(const uint2*)(e1 + (size_t)r * DIM + dp * 4);
        float acc[4];
        acc[0] = l0.x + (float)t1.h[0];
        acc[1] = l0.y + (float)t1.h[1];
        acc[2] = l0.z + (float)t1.h[2];
        acc[3] = l0.w + (float)t1.h[3];
        int len = rowLen[r];
        const int2* pp = pairs + rowStart[r];
        float a0[4] = {0.f, 0.f, 0.f, 0.f}, a1[4] = {0.f, 0.f, 0.f, 0.f};
        float a2[4] = {0.f, 0.f, 0.f, 0.f}, a3[4] = {0.f, 0.f, 0.f, 0.f};
        int k = 0;
        for (; k + 16 <= len; k += 16) {
            int4 q0 = *(const int4*)(pp + k + 2 * eg);
            int4 q1 = *(const int4*)(pp + k + 8 + 2 * eg);
            H4 g0, g1, g2, g3;
            g0.u = *(const uint2*)(base + ((unsigned)q0.x + off0));
            g1.u = *(const uint2*)(base + ((unsigned)q0.z + off0));
            g2.u = *(const uint2*)(base + ((unsigned)q1.x + off0));
            g3.u = *(const uint2*)(base + ((unsigned)q1.z + off0));
            float v0 = __int_as_float(q0.y), v1 = __int_as_float(q0.w);
            float v2 = __int_as_float(q1.y), v3 = __int_as_float(q1.w);
#pragma unroll
            for (int i = 0; i < 4; i++) {
                a0[i] += (float)g0.h[i] * v0;
                a1[i] += (float)g1.h[i] * v1;
                a2[i] += (float)g2.h[i] * v2;
                a3[i] += (float)g3.h[i] * v3;
            }
        }
        for (; k < len; k += 8) {
            int4 q0 = *(const int4*)(pp + k + 2 * eg);
            H4 g0, g1;
            g0.u = *(const uint2*)(base + ((unsigned)q0.x + off0));
            g1.u = *(const uint2*)(base + ((unsigned)q0.z + off0));
            float v0 = __int_as_float(q0.y), v1 = __int_as_float(q0.w);
#pragma unroll
            for (int i = 0; i < 4; i++) {
                a0[i] += (float)g0.h[i] * v0;
                a1[i] += (float)g1.h[i] * v1;
            }
        }
        float s[4];
#pragma unroll
        for (int i = 0; i < 4; i++) s[i] = (a0[i] + a1[i]) + (a2[i] + a3[i]);
#pragma unroll
        for (int i = 0; i < 4; i++) {
            s[i] += __shfl_xor(s[i], 16);
            s[i] += __shfl_xor(s[i], 32);
        }
#pragma unroll
        for (int i = 0; i < 4; i++) l[j][i] = (acc[i] + s[i]) * (1.0f / 3.0f);
    }
    float ps = l[0][0] * l[1][0] + l[0][1] * l[1][1] + l[0][2] * l[1][2] + l[0][3] * l[1][3];
    float ns = l[0][0] * l[2][0] + l[0][1] * l[2][1] + l[0][2] * l[2][2] + l[0][3] * l[2][3];
    ps += __shfl_xor(ps, 1); ns += __shfl_xor(ns, 1);
    ps += __shfl_xor(ps, 2); ns += __shfl_xor(ns, 2);
    ps += __shfl_xor(ps, 4); ns += __shfl_xor(ns, 4);
    ps += __shfl_xor(ps, 8); ns += __shfl_xor(ns, 8);
    if (lane == 0) {
        out[wave] = ps;
        out[B + wave] = ns;
    }
}

extern "C" void kernel_launch(void* const* d_in, const int* in_sizes, int n_in,
                              void* d_out, int out_size, void* d_ws, size_t ws_size,
                              hipStream_t stream) {
    const float* emb_user = (const float*)d_in[0];
    const float* emb_item = (const float*)d_in[1];
    const float* gvals    = (const float*)d_in[2];
    const int*   grow     = (const int*)d_in[3];
    const int*   gcol     = (const int*)d_in[4];
    const int*   unodes   = (const int*)d_in[5];
    const int*   pnodes   = (const int*)d_in[6];
    const int*   nnodes   = (const int*)d_in[7];
    float* out = (float*)d_out;

    int n_user = in_sizes[0] / DIM;
    int n_item = in_sizes[1] / DIM;
    int N = n_user + n_item;
    int E = in_sizes[2];
    int B = in_sizes[5];
    int NB = (N + RPB - 1) >> BSHIFT;
    int NBLK = (E + CHUNK - 1) / CHUNK;
    int padSlop = RPB * PADMASK;

    auto align256 = [](size_t x) { return (x + 255) & ~(size_t)255; };
    size_t embBytes = (size_t)N * DIM * 2;
    size_t countsBytes = (size_t)NBLK * NB * 4;
    size_t bdataBytes = (size_t)E * 8;
    size_t regionABytes = countsBytes > embBytes ? countsBytes : embBytes;  // counts / e1
    size_t pairsBytes = ((size_t)E + (size_t)NB * padSlop) * 8;
    size_t fixedBytes = align256((size_t)N * 4) * 2 + align256((size_t)MAXNB * 4) +
                        align256((size_t)(MAXNB + 1) * 4) + align256(pairsBytes) +
                        align256(regionABytes);
    // preferred: emb16 separate from bdata -> conv fused into p1a (before bdata exists)
    bool sepEmb = fixedBytes + align256(bdataBytes) + align256(embBytes) <= ws_size;

    char* ws = (char*)d_ws;
    size_t off = 0;
    auto alloc = [&](size_t bytes) -> void* {
        void* p = ws + off;
        off = (off + bytes + 255) & ~(size_t)255;
        return p;
    };
    int*  rowStart    = (int*)alloc((size_t)N * 4);
    int*  rowLen      = (int*)alloc((size_t)N * 4);
    int*  bucketTotal = (int*)alloc((size_t)MAXNB * 4);
    int*  bucketStart = (int*)alloc((size_t)(MAXNB + 1) * 4);
    int2* pairs       = (int2*)alloc(pairsBytes);
    int2* bdata;
    unsigned short* emb16;
    if (sepEmb) {
        bdata = (int2*)alloc(bdataBytes);
        emb16 = (unsigned short*)alloc(embBytes);
    } else {
        char* regionB = (char*)alloc(bdataBytes > embBytes ? bdataBytes : embBytes);
        bdata = (int2*)regionB;            // dead after p2
        emb16 = (unsigned short*)regionB;  // written after p2 (overlay)
    }
    char* regionA = (char*)alloc(regionABytes);
    int*            counts = (int*)regionA;  // dead after p1c
    unsigned short* e1     = (unsigned short*)regionA;
    (void)n_in; (void)out_size;

    // CSR build via two-level counting sort (no global atomics)
    int nConv = sepEmb ? CONVB : 0;
    p1a_conv<<<NBLK + nConv, 256, 0, stream>>>(grow, E, NB, counts,
                                               emb_user, emb_item, n_user * DIM, N * DIM,
                                               emb16, NBLK);
    p1b_scan<<<NB, 256, 0, stream>>>(counts, NBLK, NB, bucketTotal);
    p_scan_tot<<<1, 256, 0, stream>>>(bucketTotal, NB, bucketStart);
    p1c_scatter<<<NBLK, 256, 0, stream>>>(grow, gcol, gvals, E, NB, NBLK,
                                          counts, bucketTotal, bucketStart, bdata);
    p2_group<<<NB, 256, 0, stream>>>(bdata, bucketStart, NB, N, padSlop,
                                     rowStart, rowLen, pairs);
    if (!sepEmb)  // overlay layout: pack after bdata is dead
        conv2_k<<<2048, 256, 0, stream>>>(emb_user, emb_item, n_user * DIM, N * DIM, emb16);

    // layer-1 SpMM over all rows (e1 overlays dead counts)
    spmm1_k<<<(N + 3) / 4, 256, 0, stream>>>(emb16, rowStart, rowLen, pairs, N, e1);
    // fused layer-2 + gather + dots
    final_k<<<(B + 3) / 4, 256, 0, stream>>>(emb_user, emb_item, n_user, e1,
                                             rowStart, rowLen, pairs,
                                             unodes, pnodes, nnodes, B, out);
}